// Round 9
// baseline (2032.012 us; speedup 1.0000x reference)
//
#include <hip/hip_runtime.h>
#include <hip/hip_bf16.h>

#define NN 10000
#define NE 640000
#define SD 128
#define CONCAT 10003
#define ACT 10000
#define GRID 1024
#define BS 256
#define MAXDEG 256

typedef unsigned int u32;
typedef unsigned short u16;
typedef u16 u16x8 __attribute__((ext_vector_type(8)));
typedef float f32x4 __attribute__((ext_vector_type(4)));

__device__ __forceinline__ float bf2f_bits(u16 u) {
    return __uint_as_float(((u32)u) << 16);
}
__device__ __forceinline__ float loadF(const void* base, long idx, int bf) {
    if (bf) return bf2f_bits(((const u16*)base)[idx]);
    return ((const float*)base)[idx];
}
__device__ __forceinline__ int loadI(const void* base, long idx, int i64) {
    if (i64) return (int)((const long long*)base)[idx];
    return ((const int*)base)[idx];
}
__device__ __forceinline__ int get_xcd() {
    int x;
    asm volatile("s_getreg_b32 %0, hwreg(HW_REG_XCC_ID)" : "=s"(x));
    return x & 7;
}

// per-XCD region layout (bytes)
#define O_COLS ((size_t)1 << 16)
#define SZ_ELL ((size_t)NN * MAXDEG * 4)
#define O_WVE (O_COLS + SZ_ELL)
#define O_P0 (O_WVE + SZ_ELL)
#define SZ60 ((size_t)NN * 60 * 4)
#define SZ30 ((size_t)NN * 30 * 4)
#define O_P1 (O_P0 + SZ60)
#define O_P2 (O_P1 + SZ60)
#define O_W60 (O_P2 + SZ60)
#define O_Q0 (O_W60 + SZ60)
#define O_Q1 (O_Q0 + SZ30)
#define O_Q2 (O_Q1 + SZ30)
#define O_W30 (O_Q2 + SZ30)
#define O_R1 (O_W30 + SZ30)
#define O_R2 (O_R1 + (size_t)NN * 4)
#define O_SA (O_R2 + (size_t)NN * 4)
#define O_WV3 (O_SA + (size_t)NN * 4)
#define O_ST (O_WV3 + (size_t)NN * 4)
#define XREG ((size_t)36 * 1024 * 1024)

// barrier over the slots this thread watches (mine bitmask over tid+k*256).
// seq-numbered slots: replay/poison-safe by induction (slot overwritten at
// barriers 1..s-1 of THIS run before anyone waits on s). After pass: L1-only
// invalidate (same-XCD L2 is shared+coherent; L1 is write-through).
__device__ __forceinline__ void xbar(int* bar, int seq, u32 mine, int gid, int* ldsflag) {
    asm volatile("s_waitcnt vmcnt(0)" ::: "memory");
    __syncthreads();
    if (threadIdx.x == 0)
        __hip_atomic_store(&bar[gid], seq, __ATOMIC_RELAXED, __HIP_MEMORY_SCOPE_AGENT);
    int it = 0;
    while (true) {
        if (threadIdx.x == 0) *ldsflag = 1;
        __syncthreads();
        int ok = 1;
#pragma unroll
        for (int k = 0; k < 4; ++k)
            if (mine & (1u << k)) {
                if (__hip_atomic_load(&bar[threadIdx.x + (k << 8)], __ATOMIC_RELAXED,
                                      __HIP_MEMORY_SCOPE_AGENT) != seq)
                    ok = 0;
            }
        if (!ok) *ldsflag = 0;
        __syncthreads();
        if (*ldsflag || ++it > (1 << 20)) break;
        __builtin_amdgcn_s_sleep(4);
    }
    asm volatile("buffer_inv sc0" ::: "memory");  // invalidate vector L1 only
    __syncthreads();
}

__global__ void __launch_bounds__(BS, 4) mega(
    const void* __restrict__ x_in, const void* __restrict__ edge,
    const void* sc0, const void* sc1, const void* sc2,
    const void* __restrict__ W1, const void* __restrict__ b1,
    const void* __restrict__ W2, const void* __restrict__ b2,
    const void* __restrict__ W3, const void* __restrict__ b3,
    const void* __restrict__ Wa, const void* __restrict__ ba,
    const void* __restrict__ Wc, const void* __restrict__ bc,
    int* bar, int* xcdof, char* xbase, void* __restrict__ out) {
    __shared__ int sflags[2];
    __shared__ int ldsflag;
    __shared__ int redA[BS], redB[BS];

    const int tid = threadIdx.x, gid = blockIdx.x;
    const int lane = tid & 63, wslot = tid >> 6;
    const int myxcd = get_xcd();

    // dtype probe (per-block, deterministic)
    if (tid == 0) {
        const int* e32 = (const int*)edge;
        int cnt64 = 0;
        for (int e = 0; e < 64; ++e) {
            int lo = e32[2 * e], hi = e32[2 * e + 1];
            if (hi == 0 && lo >= 0 && lo < NN) cnt64++;
        }
        sflags[0] = (cnt64 >= 56) ? 1 : 0;
        const u32* w = (const u32*)Wa;
        int c = 0;
        for (int j = 0; j < 256; ++j) {
            u32 lo = w[j] & 0xFFFFu;
            int ex = (int)((lo >> 7) & 0xFF);
            if (ex >= 100 && ex <= 140) c++;
        }
        sflags[1] = (c >= 128) ? 1 : 0;
    }
    __syncthreads();
    const int i64f = sflags[0], bf = sflags[1];

    // ---- census: publish my XCD, global flag barrier (no fences needed:
    // only atomics communicated), then learn block->XCD map ----
    if (tid == 0)
        __hip_atomic_store(&xcdof[gid], myxcd, __ATOMIC_RELAXED, __HIP_MEMORY_SCOPE_AGENT);
    xbar(bar, 1, 0xFu, gid, &ldsflag);  // watches ALL 1024 slots

    u32 mine = 0;
    int csame = 0, cbelow = 0;
#pragma unroll
    for (int k = 0; k < 4; ++k) {
        int b = tid + (k << 8);
        int x = __hip_atomic_load(&xcdof[b], __ATOMIC_RELAXED, __HIP_MEMORY_SCOPE_AGENT);
        if (x == myxcd) {
            mine |= 1u << k;
            csame++;
            if (b < gid) cbelow++;
        }
    }
    redA[tid] = csame;
    redB[tid] = cbelow;
    __syncthreads();
    for (int off = 128; off; off >>= 1) {
        if (tid < off) {
            redA[tid] += redA[tid + off];
            redB[tid] += redB[tid + off];
        }
        __syncthreads();
    }
    const int C_x = redA[0], xrank = redB[0];
    __syncthreads();
    const bool leader = (xrank == 0);

    const int xi = xrank * BS + tid;      // thread idx within XCD
    const int xnt = C_x * BS;
    const int xw = xrank * 4 + wslot;     // wave idx within XCD
    const int xnw = C_x * 4;

    char* xr = xbase + (size_t)myxcd * XREG;
    int* cnt = (int*)xr;
    int* cols = (int*)(xr + O_COLS);
    float* wve = (float*)(xr + O_WVE);
    float* P0 = (float*)(xr + O_P0);
    float* P1 = (float*)(xr + O_P1);
    float* P2 = (float*)(xr + O_P2);
    float* W60 = (float*)(xr + O_W60);
    float* Q0 = (float*)(xr + O_Q0);
    float* Q1 = (float*)(xr + O_Q1);
    float* Q2 = (float*)(xr + O_Q2);
    float* W30 = (float*)(xr + O_W30);
    float* R1 = (float*)(xr + O_R1);
    float* R2 = (float*)(xr + O_R2);
    float* Sa = (float*)(xr + O_SA);
    float* Wv3 = (float*)(xr + O_WV3);
    float* state = (float*)(xr + O_ST);

    // ---- A: zero cnt + projection P_k = X @ W1[k] ----
    for (int i = xi; i < NN; i += xnt) cnt[i] = 0;
    {
        int o = lane < 60 ? lane : 59;
        for (int r = xw; r < NN; r += xnw) {
            float xa, xb;
            if (bf) {
                u32 wbits = ((const u32*)x_in)[(long)r * 64 + lane];
                xa = bf2f_bits((u16)(wbits & 0xFFFFu));
                xb = bf2f_bits((u16)(wbits >> 16));
            } else {
                const float* xp = (const float*)x_in + (long)r * SD + 2 * lane;
                xa = xp[0];
                xb = xp[1];
            }
            float a0 = 0.f, a1 = 0.f, a2 = 0.f;
            for (int j2 = 0; j2 < 64; ++j2) {
                float xe = __shfl(xa, j2);
                float xo = __shfl(xb, j2);
                long je = (long)(2 * j2) * 60 + o;
                long jo = (long)(2 * j2 + 1) * 60 + o;
                a0 += xe * loadF(W1, 0 * SD * 60 + je, bf) + xo * loadF(W1, 0 * SD * 60 + jo, bf);
                a1 += xe * loadF(W1, 1 * SD * 60 + je, bf) + xo * loadF(W1, 1 * SD * 60 + jo, bf);
                a2 += xe * loadF(W1, 2 * SD * 60 + je, bf) + xo * loadF(W1, 2 * SD * 60 + jo, bf);
            }
            if (lane < 60) {
                P0[(long)r * 60 + lane] = a0;
                P1[(long)r * 60 + lane] = a1;
                P2[(long)r * 60 + lane] = a2;
            }
        }
    }
    xbar(bar, 2, mine, gid, &ldsflag);

    // ---- B: ELL fill (cols only; cnt becomes in-degree) ----
    for (int e = xi; e < NE; e += xnt) {
        int s_ = loadI(edge, e, i64f);
        int d = loadI(edge, NE + e, i64f);
        int pos = __hip_atomic_fetch_add(&cnt[d], 1, __ATOMIC_RELAXED,
                                         __HIP_MEMORY_SCOPE_WORKGROUP);
        if (pos < MAXDEG) cols[(size_t)d * MAXDEG + pos] = s_;
    }
    xbar(bar, 3, mine, gid, &ldsflag);

    // ---- C: U = Lhat P2 (compute+cache w) ; W60 = P1 + 2U ----
    {
        int o = lane < 60 ? lane : 59;
        for (int r = xw; r < NN; r += xnw) {
            int cr = cnt[r];
            if (cr > MAXDEG) cr = MAXDEG;
            float rr = cr > 0 ? rsqrtf((float)cr) : 0.f;
            const int* cp = cols + (size_t)r * MAXDEG;
            float* wp = wve + (size_t)r * MAXDEG;
            float acc = 0.f;
            int p = 0;
            for (; p + 3 < cr; p += 4) {
                int s0 = cp[p], s1 = cp[p + 1], s2 = cp[p + 2], s3 = cp[p + 3];
                int c0 = cnt[s0], c1 = cnt[s1], c2 = cnt[s2], c3 = cnt[s3];
                float w0 = c0 > 0 ? -rsqrtf((float)c0) * rr : 0.f;
                float w1v = c1 > 0 ? -rsqrtf((float)c1) * rr : 0.f;
                float w2v = c2 > 0 ? -rsqrtf((float)c2) * rr : 0.f;
                float w3v = c3 > 0 ? -rsqrtf((float)c3) * rr : 0.f;
                acc += w0 * P2[(size_t)s0 * 60 + o] + w1v * P2[(size_t)s1 * 60 + o] +
                       w2v * P2[(size_t)s2 * 60 + o] + w3v * P2[(size_t)s3 * 60 + o];
                if (lane == 63) {
                    wp[p] = w0;
                    wp[p + 1] = w1v;
                    wp[p + 2] = w2v;
                    wp[p + 3] = w3v;
                }
            }
            for (; p < cr; ++p) {
                int s_ = cp[p];
                int cs = cnt[s_];
                float w = cs > 0 ? -rsqrtf((float)cs) * rr : 0.f;
                acc += w * P2[(size_t)s_ * 60 + o];
                if (lane == 63) wp[p] = w;
            }
            if (lane < 60)
                W60[(size_t)r * 60 + lane] = P1[(size_t)r * 60 + lane] + 2.f * acc;
        }
    }
    xbar(bar, 4, mine, gid, &ldsflag);

    // ---- D: V = Lhat W60 ; h1 = tanh(P0-P2+V+b1); Q_k = h1 @ W2[k] ----
    {
        int o = lane < 60 ? lane : 59;
        int o2 = lane < 30 ? lane : 29;
        for (int r = xw; r < NN; r += xnw) {
            int cr = cnt[r];
            if (cr > MAXDEG) cr = MAXDEG;
            const int* cp = cols + (size_t)r * MAXDEG;
            const float* wp = wve + (size_t)r * MAXDEG;
            float acc = 0.f;
            int p = 0;
            for (; p + 3 < cr; p += 4) {
                acc += wp[p] * W60[(size_t)cp[p] * 60 + o] +
                       wp[p + 1] * W60[(size_t)cp[p + 1] * 60 + o] +
                       wp[p + 2] * W60[(size_t)cp[p + 2] * 60 + o] +
                       wp[p + 3] * W60[(size_t)cp[p + 3] * 60 + o];
            }
            for (; p < cr; ++p) acc += wp[p] * W60[(size_t)cp[p] * 60 + o];
            float h1 = tanhf(P0[(size_t)r * 60 + o] - P2[(size_t)r * 60 + o] + acc +
                             loadF(b1, o, bf));
            float q0 = 0.f, q1 = 0.f, q2 = 0.f;
            for (int j = 0; j < 60; ++j) {
                float xj = __shfl(h1, j);
                long idx = (long)j * 30 + o2;
                q0 += xj * loadF(W2, 0 * 60 * 30 + idx, bf);
                q1 += xj * loadF(W2, 1 * 60 * 30 + idx, bf);
                q2 += xj * loadF(W2, 2 * 60 * 30 + idx, bf);
            }
            if (lane < 30) {
                Q0[(size_t)r * 30 + lane] = q0;
                Q1[(size_t)r * 30 + lane] = q1;
                Q2[(size_t)r * 30 + lane] = q2;
            }
        }
    }
    xbar(bar, 5, mine, gid, &ldsflag);

    // ---- E: U2 = Lhat Q2 ; W30 = Q1 + 2U2 (half-wave over edges) ----
    {
        int h = lane >> 5, l = lane & 31;
        int l2 = l < 30 ? l : 29;
        for (int r = xw; r < NN; r += xnw) {
            int cr = cnt[r];
            if (cr > MAXDEG) cr = MAXDEG;
            const int* cp = cols + (size_t)r * MAXDEG;
            const float* wp = wve + (size_t)r * MAXDEG;
            float acc = 0.f;
            for (int p = h; p < cr; p += 2)
                acc += wp[p] * Q2[(size_t)cp[p] * 30 + l2];
            acc += __shfl_xor(acc, 32);
            if (lane < 30)
                W30[(size_t)r * 30 + lane] = Q1[(size_t)r * 30 + lane] + 2.f * acc;
        }
    }
    xbar(bar, 6, mine, gid, &ldsflag);

    // ---- F: V2 = Lhat W30 ; h2 = tanh(Q0-Q2+V2+b2); R_k = h2 . W3[k] ----
    {
        int h = lane >> 5, l = lane & 31;
        int l2 = l < 30 ? l : 29;
        for (int r = xw; r < NN; r += xnw) {
            int cr = cnt[r];
            if (cr > MAXDEG) cr = MAXDEG;
            const int* cp = cols + (size_t)r * MAXDEG;
            const float* wp = wve + (size_t)r * MAXDEG;
            float acc = 0.f;
            for (int p = h; p < cr; p += 2)
                acc += wp[p] * W30[(size_t)cp[p] * 30 + l2];
            acc += __shfl_xor(acc, 32);
            float r0 = 0.f, r1 = 0.f, r2 = 0.f;
            if (l < 30) {
                float h2v = tanhf(Q0[(size_t)r * 30 + l] - Q2[(size_t)r * 30 + l] + acc +
                                  loadF(b2, l, bf));
                r0 = h2v * loadF(W3, 0 * 30 + l, bf);
                r1 = h2v * loadF(W3, 1 * 30 + l, bf);
                r2 = h2v * loadF(W3, 2 * 30 + l, bf);
            }
#pragma unroll
            for (int m = 16; m; m >>= 1) {
                r0 += __shfl_xor(r0, m);
                r1 += __shfl_xor(r1, m);
                r2 += __shfl_xor(r2, m);
            }
            if (lane == 0) {
                R1[r] = r1;
                R2[r] = r2;
                Sa[r] = r0 - r2;
            }
        }
    }
    xbar(bar, 7, mine, gid, &ldsflag);

    // ---- G: U3 = Lhat R2 ; Wv3 = R1 + 2U3 (lanes over edges) ----
    {
        for (int r = xw; r < NN; r += xnw) {
            int cr = cnt[r];
            if (cr > MAXDEG) cr = MAXDEG;
            const int* cp = cols + (size_t)r * MAXDEG;
            const float* wp = wve + (size_t)r * MAXDEG;
            float acc = 0.f;
            for (int p = lane; p < cr; p += 64) acc += wp[p] * R2[cp[p]];
#pragma unroll
            for (int m = 32; m; m >>= 1) acc += __shfl_xor(acc, m);
            if (lane == 0) Wv3[r] = R1[r] + 2.f * acc;
        }
    }
    xbar(bar, 8, mine, gid, &ldsflag);

    // ---- H: V3 = Lhat Wv3 ; state = tanh(Sa + V3 + b3) ; tail scalars ----
    {
        for (int r = xw; r < NN; r += xnw) {
            int cr = cnt[r];
            if (cr > MAXDEG) cr = MAXDEG;
            const int* cp = cols + (size_t)r * MAXDEG;
            const float* wp = wve + (size_t)r * MAXDEG;
            float acc = 0.f;
            for (int p = lane; p < cr; p += 64) acc += wp[p] * Wv3[cp[p]];
#pragma unroll
            for (int m = 32; m; m >>= 1) acc += __shfl_xor(acc, m);
            if (lane == 0) state[r] = tanhf(Sa[r] + acc + loadF(b3, 0, bf));
        }
        if (leader && tid == 0) {
            state[10000] = loadF(sc0, 0, bf);
            state[10001] = loadF(sc1, 0, bf);
            state[10002] = loadF(sc2, 0, bf);
        }
    }
    xbar(bar, 9, mine, gid, &ldsflag);

    // ---- I: heads — GLOBAL row split, each block reads its LOCAL state replica ----
    {
        int wid_g = gid * 4 + wslot;
        for (int r = wid_g; r <= ACT; r += GRID * 4) {
            long base = (r < ACT) ? (long)r * CONCAT : 0;
            const void* wb = (r < ACT) ? Wa : Wc;
            float acc = 0.f;
            if (bf) {
                const u16* w = (const u16*)wb + base;
                int k = (int)((16 - ((2 * base) & 15)) & 15) >> 1;
                for (int i = lane; i < k; i += 64) acc += state[i] * bf2f_bits(w[i]);
                int nv = (CONCAT - k) >> 3;
                const u16x8* wvp = (const u16x8*)(w + k);
                for (int v = lane; v < nv; v += 64) {
                    u16x8 ww = wvp[v];
                    int ib = k + v * 8;
#pragma unroll
                    for (int j = 0; j < 8; ++j) acc += state[ib + j] * bf2f_bits(ww[j]);
                }
                for (int i = k + nv * 8 + lane; i < CONCAT; i += 64)
                    acc += state[i] * bf2f_bits(w[i]);
            } else {
                const float* w = (const float*)wb + base;
                int k = (int)((16 - ((4 * base) & 15)) & 15) >> 2;
                for (int i = lane; i < k; i += 64) acc += state[i] * w[i];
                int nv = (CONCAT - k) >> 2;
                const f32x4* wvp = (const f32x4*)(w + k);
                for (int v = lane; v < nv; v += 64) {
                    f32x4 ww = wvp[v];
                    int ib = k + v * 4;
#pragma unroll
                    for (int j = 0; j < 4; ++j) acc += state[ib + j] * ww[j];
                }
                for (int i = k + nv * 4 + lane; i < CONCAT; i += 64)
                    acc += state[i] * w[i];
            }
#pragma unroll
            for (int o = 32; o > 0; o >>= 1) acc += __shfl_xor(acc, o);
            if (lane == 0) {
                float bias = (r < ACT) ? loadF(ba, r, bf) : loadF(bc, 0, bf);
                float v = acc + bias;
                if (bf) ((__hip_bfloat16*)out)[r] = __float2bfloat16(v);
                else ((float*)out)[r] = v;
            }
        }
    }
}

extern "C" void kernel_launch(void* const* d_in, const int* in_sizes, int n_in,
                              void* d_out, int out_size, void* d_ws, size_t ws_size,
                              hipStream_t stream) {
    char* p = (char*)d_ws;
    auto alloc = [&](size_t bytes) {
        char* r = p;
        p += (bytes + 255) & ~(size_t)255;
        return (void*)r;
    };
    int* bar = (int*)alloc(GRID * 4);
    int* xcdof = (int*)alloc(GRID * 4);
    char* xbase = (char*)alloc(8 * XREG);

    mega<<<GRID, BS, 0, stream>>>(
        d_in[0], d_in[1], d_in[2], d_in[3], d_in[4], d_in[5], d_in[6], d_in[7],
        d_in[8], d_in[9], d_in[10], d_in[11], d_in[12], d_in[13], d_in[14],
        bar, xcdof, xbase, d_out);
}

// Round 10
// 351.864 us; speedup vs baseline: 5.7750x; 5.7750x over previous
//
#include <hip/hip_runtime.h>
#include <hip/hip_bf16.h>

#define NN 10000
#define NE 640000
#define SD 128
#define CONCAT 10003
#define ACT 10000
#define MAXDEG 256
#define GB 2500            // blocks for graph/row kernels (10000 waves)
#define HB 2512            // heads blocks (10048 waves)

typedef unsigned int u32;
typedef unsigned short u16;
typedef u16 u16x8 __attribute__((ext_vector_type(8)));
typedef float f32x4 __attribute__((ext_vector_type(4)));

__device__ __forceinline__ float bf2f_bits(u16 u) {
    return __uint_as_float(((u32)u) << 16);
}
__device__ __forceinline__ float loadF(const void* base, long idx, int bf) {
    if (bf) return bf2f_bits(((const u16*)base)[idx]);
    return ((const float*)base)[idx];
}
__device__ __forceinline__ int loadI(const void* base, long idx, int i64) {
    if (i64) return (int)((const long long*)base)[idx];
    return ((const int*)base)[idx];
}

// ---- k_prep: probe dtypes (block0 -> global flags), zero cnt, P_k = X@W1[k] ----
__global__ void __launch_bounds__(256) k_prep(
    const void* __restrict__ x_in, const void* __restrict__ W1,
    const void* __restrict__ Wa, const void* __restrict__ edge,
    int* __restrict__ flags, int* __restrict__ cnt,
    float* __restrict__ P0, float* __restrict__ P1, float* __restrict__ P2) {
    __shared__ int sbf;
    const int tid = threadIdx.x, gid = blockIdx.x;
    const int gtid = gid * 256 + tid;
    const int lane = tid & 63;
    const int wid = gid * 4 + (tid >> 6);

    if (tid == 0) {
        const u32* w = (const u32*)Wa;
        int c = 0;
        for (int j = 0; j < 256; ++j) {
            u32 lo = w[j] & 0xFFFFu;
            int ex = (int)((lo >> 7) & 0xFF);
            if (ex >= 100 && ex <= 140) c++;
        }
        sbf = (c >= 128) ? 1 : 0;
        if (gid == 0) {
            const int* e32 = (const int*)edge;
            int cnt64 = 0;
            for (int e = 0; e < 64; ++e) {
                int lo = e32[2 * e], hi = e32[2 * e + 1];
                if (hi == 0 && lo >= 0 && lo < NN) cnt64++;
            }
            flags[0] = (cnt64 >= 56) ? 1 : 0;
            flags[1] = sbf;
        }
    }
    __syncthreads();
    const int bf = sbf;

    for (int i = gtid; i < NN; i += GB * 256) cnt[i] = 0;

    int o = lane < 60 ? lane : 59;
    for (int r = wid; r < NN; r += GB * 4) {
        float xa, xb;
        if (bf) {
            u32 wbits = ((const u32*)x_in)[(long)r * 64 + lane];
            xa = bf2f_bits((u16)(wbits & 0xFFFFu));
            xb = bf2f_bits((u16)(wbits >> 16));
        } else {
            const float* xp = (const float*)x_in + (long)r * SD + 2 * lane;
            xa = xp[0];
            xb = xp[1];
        }
        float a0 = 0.f, a1 = 0.f, a2 = 0.f;
        for (int j2 = 0; j2 < 64; ++j2) {
            float xe = __shfl(xa, j2);
            float xo = __shfl(xb, j2);
            long je = (long)(2 * j2) * 60 + o;
            long jo = (long)(2 * j2 + 1) * 60 + o;
            a0 += xe * loadF(W1, 0 * SD * 60 + je, bf) + xo * loadF(W1, 0 * SD * 60 + jo, bf);
            a1 += xe * loadF(W1, 1 * SD * 60 + je, bf) + xo * loadF(W1, 1 * SD * 60 + jo, bf);
            a2 += xe * loadF(W1, 2 * SD * 60 + je, bf) + xo * loadF(W1, 2 * SD * 60 + jo, bf);
        }
        if (lane < 60) {
            P0[(long)r * 60 + lane] = a0;
            P1[(long)r * 60 + lane] = a1;
            P2[(long)r * 60 + lane] = a2;
        }
    }
}

// ---- k_fill: ELL fill; cnt becomes in-degree ----
__global__ void __launch_bounds__(256) k_fill(
    const void* __restrict__ edge, const int* __restrict__ flags,
    int* __restrict__ cnt, int* __restrict__ cols) {
    const int i64f = flags[0];
    int e = blockIdx.x * 256 + threadIdx.x;
    for (; e < NE; e += GB * 256) {
        int s = loadI(edge, e, i64f);
        int d = loadI(edge, NE + e, i64f);
        int pos = atomicAdd(&cnt[d], 1);
        if (pos < MAXDEG) cols[(size_t)d * MAXDEG + pos] = s;
    }
}

// ---- k_s1: U = Lhat P2 (compute + cache weights) ; W60 = P1 + 2U ----
__global__ void __launch_bounds__(256) k_s1(
    const int* __restrict__ cnt, const int* __restrict__ cols,
    float* __restrict__ wve, const float* __restrict__ P1,
    const float* __restrict__ P2, float* __restrict__ W60) {
    const int tid = threadIdx.x;
    const int lane = tid & 63;
    const int wid = blockIdx.x * 4 + (tid >> 6);
    int o = lane < 60 ? lane : 59;
    for (int r = wid; r < NN; r += GB * 4) {
        int cr = cnt[r];
        if (cr > MAXDEG) cr = MAXDEG;
        float rr = cr > 0 ? rsqrtf((float)cr) : 0.f;
        const int* cp = cols + (size_t)r * MAXDEG;
        float* wp = wve + (size_t)r * MAXDEG;
        float acc = 0.f;
        int p = 0;
        for (; p + 3 < cr; p += 4) {
            int s0 = cp[p], s1 = cp[p + 1], s2 = cp[p + 2], s3 = cp[p + 3];
            int c0 = cnt[s0], c1 = cnt[s1], c2 = cnt[s2], c3 = cnt[s3];
            float w0 = c0 > 0 ? -rsqrtf((float)c0) * rr : 0.f;
            float w1 = c1 > 0 ? -rsqrtf((float)c1) * rr : 0.f;
            float w2 = c2 > 0 ? -rsqrtf((float)c2) * rr : 0.f;
            float w3 = c3 > 0 ? -rsqrtf((float)c3) * rr : 0.f;
            acc += w0 * P2[(size_t)s0 * 60 + o] + w1 * P2[(size_t)s1 * 60 + o] +
                   w2 * P2[(size_t)s2 * 60 + o] + w3 * P2[(size_t)s3 * 60 + o];
            if (lane == 63) {
                wp[p] = w0;
                wp[p + 1] = w1;
                wp[p + 2] = w2;
                wp[p + 3] = w3;
            }
        }
        for (; p < cr; ++p) {
            int s = cp[p];
            int cs = cnt[s];
            float w = cs > 0 ? -rsqrtf((float)cs) * rr : 0.f;
            acc += w * P2[(size_t)s * 60 + o];
            if (lane == 63) wp[p] = w;
        }
        if (lane < 60)
            W60[(size_t)r * 60 + lane] = P1[(size_t)r * 60 + lane] + 2.f * acc;
    }
}

// ---- k_s2: V = Lhat W60 ; h1 = tanh(P0-P2+V+b1) ; Q_k = h1 @ W2[k] ----
__global__ void __launch_bounds__(256) k_s2(
    const int* __restrict__ cnt, const int* __restrict__ cols,
    const float* __restrict__ wve, const float* __restrict__ P0,
    const float* __restrict__ P2, const float* __restrict__ W60,
    const void* __restrict__ W2, const void* __restrict__ b1,
    const int* __restrict__ flags, float* __restrict__ Q0,
    float* __restrict__ Q1, float* __restrict__ Q2) {
    const int bf = flags[1];
    const int tid = threadIdx.x;
    const int lane = tid & 63;
    const int wid = blockIdx.x * 4 + (tid >> 6);
    int o = lane < 60 ? lane : 59;
    int o2 = lane < 30 ? lane : 29;
    for (int r = wid; r < NN; r += GB * 4) {
        int cr = cnt[r];
        if (cr > MAXDEG) cr = MAXDEG;
        const int* cp = cols + (size_t)r * MAXDEG;
        const float* wp = wve + (size_t)r * MAXDEG;
        float acc = 0.f;
        int p = 0;
        for (; p + 3 < cr; p += 4) {
            acc += wp[p] * W60[(size_t)cp[p] * 60 + o] +
                   wp[p + 1] * W60[(size_t)cp[p + 1] * 60 + o] +
                   wp[p + 2] * W60[(size_t)cp[p + 2] * 60 + o] +
                   wp[p + 3] * W60[(size_t)cp[p + 3] * 60 + o];
        }
        for (; p < cr; ++p) acc += wp[p] * W60[(size_t)cp[p] * 60 + o];
        float h1 = tanhf(P0[(size_t)r * 60 + o] - P2[(size_t)r * 60 + o] + acc +
                         loadF(b1, o, bf));
        float q0 = 0.f, q1 = 0.f, q2 = 0.f;
        for (int j = 0; j < 60; ++j) {
            float xj = __shfl(h1, j);
            long idx = (long)j * 30 + o2;
            q0 += xj * loadF(W2, 0 * 60 * 30 + idx, bf);
            q1 += xj * loadF(W2, 1 * 60 * 30 + idx, bf);
            q2 += xj * loadF(W2, 2 * 60 * 30 + idx, bf);
        }
        if (lane < 30) {
            Q0[(size_t)r * 30 + lane] = q0;
            Q1[(size_t)r * 30 + lane] = q1;
            Q2[(size_t)r * 30 + lane] = q2;
        }
    }
}

// ---- k_s3: U2 = Lhat Q2 ; W30 = Q1 + 2U2 (half-wave over edges) ----
__global__ void __launch_bounds__(256) k_s3(
    const int* __restrict__ cnt, const int* __restrict__ cols,
    const float* __restrict__ wve, const float* __restrict__ Q1,
    const float* __restrict__ Q2, float* __restrict__ W30) {
    const int tid = threadIdx.x;
    const int lane = tid & 63;
    const int wid = blockIdx.x * 4 + (tid >> 6);
    int h = lane >> 5, l = lane & 31;
    int l2 = l < 30 ? l : 29;
    for (int r = wid; r < NN; r += GB * 4) {
        int cr = cnt[r];
        if (cr > MAXDEG) cr = MAXDEG;
        const int* cp = cols + (size_t)r * MAXDEG;
        const float* wp = wve + (size_t)r * MAXDEG;
        float acc = 0.f;
        for (int p = h; p < cr; p += 2) acc += wp[p] * Q2[(size_t)cp[p] * 30 + l2];
        acc += __shfl_xor(acc, 32);
        if (lane < 30)
            W30[(size_t)r * 30 + lane] = Q1[(size_t)r * 30 + lane] + 2.f * acc;
    }
}

// ---- k_s4: V2 = Lhat W30 ; h2 = tanh(Q0-Q2+V2+b2) ; R_k = h2 . W3[k] ----
__global__ void __launch_bounds__(256) k_s4(
    const int* __restrict__ cnt, const int* __restrict__ cols,
    const float* __restrict__ wve, const float* __restrict__ Q0,
    const float* __restrict__ Q2, const float* __restrict__ W30,
    const void* __restrict__ W3, const void* __restrict__ b2,
    const int* __restrict__ flags, float* __restrict__ R1,
    float* __restrict__ R2, float* __restrict__ Sa) {
    const int bf = flags[1];
    const int tid = threadIdx.x;
    const int lane = tid & 63;
    const int wid = blockIdx.x * 4 + (tid >> 6);
    int h = lane >> 5, l = lane & 31;
    int l2 = l < 30 ? l : 29;
    for (int r = wid; r < NN; r += GB * 4) {
        int cr = cnt[r];
        if (cr > MAXDEG) cr = MAXDEG;
        const int* cp = cols + (size_t)r * MAXDEG;
        const float* wp = wve + (size_t)r * MAXDEG;
        float acc = 0.f;
        for (int p = h; p < cr; p += 2) acc += wp[p] * W30[(size_t)cp[p] * 30 + l2];
        acc += __shfl_xor(acc, 32);
        float r0 = 0.f, r1 = 0.f, r2 = 0.f;
        if (l < 30) {
            float h2v = tanhf(Q0[(size_t)r * 30 + l] - Q2[(size_t)r * 30 + l] + acc +
                              loadF(b2, l, bf));
            r0 = h2v * loadF(W3, 0 * 30 + l, bf);
            r1 = h2v * loadF(W3, 1 * 30 + l, bf);
            r2 = h2v * loadF(W3, 2 * 30 + l, bf);
        }
#pragma unroll
        for (int m = 16; m; m >>= 1) {
            r0 += __shfl_xor(r0, m);
            r1 += __shfl_xor(r1, m);
            r2 += __shfl_xor(r2, m);
        }
        if (lane == 0) {
            R1[r] = r1;
            R2[r] = r2;
            Sa[r] = r0 - r2;
        }
    }
}

// ---- k_s5: U3 = Lhat R2 ; Wv3 = R1 + 2U3 ----
__global__ void __launch_bounds__(256) k_s5(
    const int* __restrict__ cnt, const int* __restrict__ cols,
    const float* __restrict__ wve, const float* __restrict__ R1,
    const float* __restrict__ R2, float* __restrict__ Wv3) {
    const int tid = threadIdx.x;
    const int lane = tid & 63;
    const int wid = blockIdx.x * 4 + (tid >> 6);
    for (int r = wid; r < NN; r += GB * 4) {
        int cr = cnt[r];
        if (cr > MAXDEG) cr = MAXDEG;
        const int* cp = cols + (size_t)r * MAXDEG;
        const float* wp = wve + (size_t)r * MAXDEG;
        float acc = 0.f;
        for (int p = lane; p < cr; p += 64) acc += wp[p] * R2[cp[p]];
#pragma unroll
        for (int m = 32; m; m >>= 1) acc += __shfl_xor(acc, m);
        if (lane == 0) Wv3[r] = R1[r] + 2.f * acc;
    }
}

// ---- k_s6: V3 = Lhat Wv3 ; state = tanh(Sa+V3+b3) ; tail scalars ----
__global__ void __launch_bounds__(256) k_s6(
    const int* __restrict__ cnt, const int* __restrict__ cols,
    const float* __restrict__ wve, const float* __restrict__ Sa,
    const float* __restrict__ Wv3, const void* __restrict__ b3,
    const void* sc0, const void* sc1, const void* sc2,
    const int* __restrict__ flags, float* __restrict__ state) {
    const int bf = flags[1];
    const int tid = threadIdx.x;
    const int lane = tid & 63;
    const int wid = blockIdx.x * 4 + (tid >> 6);
    for (int r = wid; r < NN; r += GB * 4) {
        int cr = cnt[r];
        if (cr > MAXDEG) cr = MAXDEG;
        const int* cp = cols + (size_t)r * MAXDEG;
        const float* wp = wve + (size_t)r * MAXDEG;
        float acc = 0.f;
        for (int p = lane; p < cr; p += 64) acc += wp[p] * Wv3[cp[p]];
#pragma unroll
        for (int m = 32; m; m >>= 1) acc += __shfl_xor(acc, m);
        if (lane == 0) state[r] = tanhf(Sa[r] + acc + loadF(b3, 0, bf));
    }
    if (blockIdx.x == 0 && tid == 0) {
        state[10000] = loadF(sc0, 0, bf);
        state[10001] = loadF(sc1, 0, bf);
        state[10002] = loadF(sc2, 0, bf);
    }
}

// ---- k_heads: wave per row ----
__global__ void __launch_bounds__(256) k_heads(
    const float* __restrict__ state, const void* __restrict__ Wa,
    const void* __restrict__ ba, const void* __restrict__ Wc,
    const void* __restrict__ bc, const int* __restrict__ flags,
    void* __restrict__ out) {
    const int bf = flags[1];
    const int tid = threadIdx.x;
    const int lane = tid & 63;
    const int wid = blockIdx.x * 4 + (tid >> 6);
    for (int r = wid; r <= ACT; r += HB * 4) {
        long base = (r < ACT) ? (long)r * CONCAT : 0;
        const void* wb = (r < ACT) ? Wa : Wc;
        float acc = 0.f;
        if (bf) {
            const u16* w = (const u16*)wb + base;
            int k = (int)((16 - ((2 * base) & 15)) & 15) >> 1;
            for (int i = lane; i < k; i += 64) acc += state[i] * bf2f_bits(w[i]);
            int nv = (CONCAT - k) >> 3;
            const u16x8* wvp = (const u16x8*)(w + k);
            for (int v = lane; v < nv; v += 64) {
                u16x8 ww = wvp[v];
                int ib = k + v * 8;
#pragma unroll
                for (int j = 0; j < 8; ++j) acc += state[ib + j] * bf2f_bits(ww[j]);
            }
            for (int i = k + nv * 8 + lane; i < CONCAT; i += 64)
                acc += state[i] * bf2f_bits(w[i]);
        } else {
            const float* w = (const float*)wb + base;
            int k = (int)((16 - ((4 * base) & 15)) & 15) >> 2;
            for (int i = lane; i < k; i += 64) acc += state[i] * w[i];
            int nv = (CONCAT - k) >> 2;
            const f32x4* wvp = (const f32x4*)(w + k);
            for (int v = lane; v < nv; v += 64) {
                f32x4 ww = wvp[v];
                int ib = k + v * 4;
#pragma unroll
                for (int j = 0; j < 4; ++j) acc += state[ib + j] * ww[j];
            }
            for (int i = k + nv * 4 + lane; i < CONCAT; i += 64)
                acc += state[i] * w[i];
        }
#pragma unroll
        for (int o = 32; o > 0; o >>= 1) acc += __shfl_xor(acc, o);
        if (lane == 0) {
            float bias = (r < ACT) ? loadF(ba, r, bf) : loadF(bc, 0, bf);
            float v = acc + bias;
            if (bf) ((__hip_bfloat16*)out)[r] = __float2bfloat16(v);
            else ((float*)out)[r] = v;
        }
    }
}

extern "C" void kernel_launch(void* const* d_in, const int* in_sizes, int n_in,
                              void* d_out, int out_size, void* d_ws, size_t ws_size,
                              hipStream_t stream) {
    const void* x_in = d_in[0];
    const void* edge = d_in[1];
    const void* sc0 = d_in[2];
    const void* sc1 = d_in[3];
    const void* sc2 = d_in[4];
    const void* W1 = d_in[5];
    const void* b1 = d_in[6];
    const void* W2 = d_in[7];
    const void* b2 = d_in[8];
    const void* W3 = d_in[9];
    const void* b3 = d_in[10];
    const void* Wa = d_in[11];
    const void* ba = d_in[12];
    const void* Wc = d_in[13];
    const void* bc = d_in[14];

    char* p = (char*)d_ws;
    auto alloc = [&](size_t bytes) {
        char* r = p;
        p += (bytes + 255) & ~(size_t)255;
        return (void*)r;
    };
    int* flags = (int*)alloc(2 * 4);
    int* cnt = (int*)alloc(NN * 4);
    int* cols = (int*)alloc((size_t)NN * MAXDEG * 4);
    float* wve = (float*)alloc((size_t)NN * MAXDEG * 4);
    float* P0 = (float*)alloc((size_t)NN * 60 * 4);
    float* P1 = (float*)alloc((size_t)NN * 60 * 4);
    float* P2 = (float*)alloc((size_t)NN * 60 * 4);
    float* W60 = (float*)alloc((size_t)NN * 60 * 4);
    float* Q0 = (float*)alloc((size_t)NN * 30 * 4);
    float* Q1 = (float*)alloc((size_t)NN * 30 * 4);
    float* Q2 = (float*)alloc((size_t)NN * 30 * 4);
    float* W30 = (float*)alloc((size_t)NN * 30 * 4);
    float* R1 = (float*)alloc(NN * 4);
    float* R2 = (float*)alloc(NN * 4);
    float* Sa = (float*)alloc(NN * 4);
    float* Wv3 = (float*)alloc(NN * 4);
    float* state = (float*)alloc(CONCAT * 4);

    k_prep<<<GB, 256, 0, stream>>>(x_in, W1, Wa, edge, flags, cnt, P0, P1, P2);
    k_fill<<<GB, 256, 0, stream>>>(edge, flags, cnt, cols);
    k_s1<<<GB, 256, 0, stream>>>(cnt, cols, wve, P1, P2, W60);
    k_s2<<<GB, 256, 0, stream>>>(cnt, cols, wve, P0, P2, W60, W2, b1, flags, Q0, Q1, Q2);
    k_s3<<<GB, 256, 0, stream>>>(cnt, cols, wve, Q1, Q2, W30);
    k_s4<<<GB, 256, 0, stream>>>(cnt, cols, wve, Q0, Q2, W30, W3, b2, flags, R1, R2, Sa);
    k_s5<<<GB, 256, 0, stream>>>(cnt, cols, wve, R1, R2, Wv3);
    k_s6<<<GB, 256, 0, stream>>>(cnt, cols, wve, Sa, Wv3, b3, sc0, sc1, sc2, flags, state);
    k_heads<<<HB, 256, 0, stream>>>(state, Wa, ba, Wc, bc, flags, d_out);
}